// Round 5
// baseline (585.897 us; speedup 1.0000x reference)
//
#include <hip/hip_runtime.h>

using u16 = unsigned short;
using u32 = unsigned int;

typedef __attribute__((ext_vector_type(8))) __bf16 bf16x8;
typedef __attribute__((ext_vector_type(4))) float f32x4;

#define DEVI __device__ __forceinline__

DEVI float bf2f(u16 u) {
  union { u32 i; float f; } v; v.i = ((u32)u) << 16; return v.f;
}
DEVI u16 f2bf(float f) {
  union { float f; u32 u; } v; v.f = f;
  u32 u = v.u;
  u32 r = (u + 0x7fffu + ((u >> 16) & 1u)) >> 16;
  return (u16)r;
}

// ------- transpose+convert: in[R][Cc] fp32 -> out[Cc][R] bf16 -------
__global__ __launch_bounds__(256) void transpose_cvt(const float* __restrict__ in,
                                                     u16* __restrict__ out,
                                                     int R, int Cc) {
  __shared__ u16 tile[32][33];
  int c0 = blockIdx.x * 32, r0 = blockIdx.y * 32;
  int x  = threadIdx.x & 31;
  int y0 = threadIdx.x >> 5;  // 0..7
  for (int yy = y0; yy < 32; yy += 8)
    tile[yy][x] = f2bf(in[(size_t)(r0 + yy) * Cc + c0 + x]);
  __syncthreads();
  for (int yy = y0; yy < 32; yy += 8)
    out[(size_t)(c0 + yy) * R + r0 + x] = tile[x][yy];
}

// ---------------- transpose bf16 (internal buffers) ----------------
__global__ __launch_bounds__(256) void transpose_bf16(const u16* __restrict__ in,
                                                      u16* __restrict__ out,
                                                      int R, int Cc) {
  __shared__ u16 tile[32][33];
  int c0 = blockIdx.x * 32, r0 = blockIdx.y * 32;
  int x  = threadIdx.x & 31;
  int y0 = threadIdx.x >> 5;
  for (int yy = y0; yy < 32; yy += 8)
    tile[yy][x] = in[(size_t)(r0 + yy) * Cc + c0 + x];
  __syncthreads();
  for (int yy = y0; yy < 32; yy += 8)
    out[(size_t)(c0 + yy) * R + r0 + x] = tile[x][yy];
}

// ---- GEMM: C[M,N] = A[M,K](fp32) * Bt[N,K](bf16)^T, bf16 out, fp32 acc ----
__global__ __launch_bounds__(256) void gemm_a32_bt(const float* __restrict__ A,
                                                   const u16* __restrict__ Bt,
                                                   u16* __restrict__ Cmat,
                                                   int M, int N, int K) {
  constexpr int LDT = 40;
  __shared__ u16 As[64 * LDT];
  __shared__ u16 Bs[64 * LDT];
  int tid  = threadIdx.x;
  int wid  = tid >> 6;
  int lane = tid & 63;
  int quad = lane >> 4;
  int l15  = lane & 15;
  int m0 = blockIdx.y * 64;
  int n0 = blockIdx.x * 64;
  int wm = (wid >> 1) * 32;
  int wn = (wid & 1) * 32;

  int sr = tid >> 2;         // 0..63
  int sc = (tid & 3) * 8;    // 0,8,16,24

  f32x4 acc[2][2];
  for (int i = 0; i < 2; i++)
    for (int j = 0; j < 2; j++)
      acc[i][j] = f32x4{0.f, 0.f, 0.f, 0.f};

  const float* Aptr = A + (size_t)(m0 + sr) * K + sc;
  const u16*   Bptr = Bt + (size_t)(n0 + sr) * K + sc;
  u16* AsW = As + sr * LDT + sc;
  u16* BsW = Bs + sr * LDT + sc;

  for (int k0 = 0; k0 < K; k0 += 32) {
    float4 a0 = *(const float4*)(Aptr + k0);
    float4 a1 = *(const float4*)(Aptr + k0 + 4);
    uint4  bv = *(const uint4*)(Bptr + k0);
    u16 ac[8] = {f2bf(a0.x), f2bf(a0.y), f2bf(a0.z), f2bf(a0.w),
                 f2bf(a1.x), f2bf(a1.y), f2bf(a1.z), f2bf(a1.w)};
    __syncthreads();  // prior iter's frag reads done
    *(uint4*)AsW = *(const uint4*)ac;
    *(uint4*)BsW = bv;
    __syncthreads();
    bf16x8 af[2], bff[2];
    for (int mi = 0; mi < 2; mi++)
      af[mi] = *(const bf16x8*)(As + (wm + mi * 16 + l15) * LDT + quad * 8);
    for (int ni = 0; ni < 2; ni++)
      bff[ni] = *(const bf16x8*)(Bs + (wn + ni * 16 + l15) * LDT + quad * 8);
    for (int mi = 0; mi < 2; mi++)
      for (int ni = 0; ni < 2; ni++)
        acc[mi][ni] = __builtin_amdgcn_mfma_f32_16x16x32_bf16(af[mi], bff[ni], acc[mi][ni], 0, 0, 0);
  }
  for (int mi = 0; mi < 2; mi++)
    for (int ni = 0; ni < 2; ni++)
      for (int r = 0; r < 4; r++) {
        int row = m0 + wm + mi * 16 + quad * 4 + r;
        int col = n0 + wn + ni * 16 + l15;
        Cmat[(size_t)row * N + col] = f2bf(acc[mi][ni][r]);
      }
}

// ---- GEMM: C[M,N](fp32) = A[M,K](bf16) * Bt[N,K](bf16)^T ----
__global__ __launch_bounds__(256) void gemm_bt_f32out(const u16* __restrict__ A,
                                                      const u16* __restrict__ Bt,
                                                      float* __restrict__ Cmat,
                                                      int M, int N, int K) {
  constexpr int LDT = 40;
  __shared__ u16 As[64 * LDT];
  __shared__ u16 Bs[64 * LDT];
  int tid  = threadIdx.x;
  int wid  = tid >> 6;
  int lane = tid & 63;
  int quad = lane >> 4;
  int l15  = lane & 15;
  int m0 = blockIdx.y * 64;
  int n0 = blockIdx.x * 64;
  int wm = (wid >> 1) * 32;
  int wn = (wid & 1) * 32;

  int sr = tid >> 2;
  int sc = (tid & 3) * 8;

  f32x4 acc[2][2];
  for (int i = 0; i < 2; i++)
    for (int j = 0; j < 2; j++)
      acc[i][j] = f32x4{0.f, 0.f, 0.f, 0.f};

  const u16* Aptr = A  + (size_t)(m0 + sr) * K + sc;
  const u16* Bptr = Bt + (size_t)(n0 + sr) * K + sc;
  u16* AsW = As + sr * LDT + sc;
  u16* BsW = Bs + sr * LDT + sc;

  for (int k0 = 0; k0 < K; k0 += 32) {
    uint4 av = *(const uint4*)(Aptr + k0);
    uint4 bv = *(const uint4*)(Bptr + k0);
    __syncthreads();
    *(uint4*)AsW = av;
    *(uint4*)BsW = bv;
    __syncthreads();
    bf16x8 af[2], bff[2];
    for (int mi = 0; mi < 2; mi++)
      af[mi] = *(const bf16x8*)(As + (wm + mi * 16 + l15) * LDT + quad * 8);
    for (int ni = 0; ni < 2; ni++)
      bff[ni] = *(const bf16x8*)(Bs + (wn + ni * 16 + l15) * LDT + quad * 8);
    for (int mi = 0; mi < 2; mi++)
      for (int ni = 0; ni < 2; ni++)
        acc[mi][ni] = __builtin_amdgcn_mfma_f32_16x16x32_bf16(af[mi], bff[ni], acc[mi][ni], 0, 0, 0);
  }
  for (int mi = 0; mi < 2; mi++)
    for (int ni = 0; ni < 2; ni++)
      for (int r = 0; r < 4; r++) {
        int row = m0 + wm + mi * 16 + quad * 4 + r;
        int col = n0 + wn + ni * 16 + l15;
        Cmat[(size_t)row * N + col] = acc[mi][ni][r];   // fp32 out, no rounding
      }
}

// ---------------- RoPE in place on [4096][width], heads of 64 ----------------
__global__ __launch_bounds__(256) void rope_kernel(u16* __restrict__ X, int width, int total) {
  int idx = blockIdx.x * 256 + threadIdx.x;
  if (idx >= total) return;
  int ppr  = width >> 1;
  int row  = idx / ppr;
  int rem  = idx - row * ppr;
  int head = rem >> 5;
  int d    = rem & 31;
  int t    = row & 2047;            // row = b*T + t, T=2048
  float inv = exp2f(-(float)d * 0.59161152f);  // 500000^(-d/32)
  float ang = (float)t * inv;
  float s, c;
  sincosf(ang, &s, &c);
  size_t base = (size_t)row * width + head * 64 + d;
  float x0 = bf2f(X[base]);
  float x1 = bf2f(X[base + 32]);
  X[base]      = f2bf(x0 * c - x1 * s);
  X[base + 32] = f2bf(x1 * c + x0 * s);
}

// ---------------- Flash attention (no-max online softmax) ----------------
// grid: (T/64, B*H). Block 256 = 4 waves; wave w owns queries t0+16w .. +15.
__global__ __launch_bounds__(256) void attn_kernel(const u16* __restrict__ Q,
                                                   const u16* __restrict__ Kb,
                                                   const u16* __restrict__ Vt,
                                                   u16* __restrict__ Y) {
  constexpr int KLD = 72;
  constexpr int VLD = 40;
  constexpr int PLD = 40;
  __shared__ u16 Ks[32 * KLD];     // [key][d]
  __shared__ u16 Vst[64 * VLD];    // [d][key]
  __shared__ u16 Ps[4][16 * PLD];  // per-wave [q][key]

  int tid  = threadIdx.x;
  int wid  = tid >> 6;
  int lane = tid & 63;
  int quad = lane >> 4;
  int l15  = lane & 15;
  int bh = blockIdx.y;
  int b  = bh >> 5;
  int h  = bh & 31;
  int kvh = h >> 2;
  int t0  = blockIdx.x * 64;
  int qrow = t0 + wid * 16;

  bf16x8 qf[2];
  {
    const u16* qp = Q + (size_t)(b * 2048 + qrow + l15) * 2048 + h * 64 + quad * 8;
    qf[0] = *(const bf16x8*)(qp);
    qf[1] = *(const bf16x8*)(qp + 32);
  }

  f32x4 o[4];
  for (int i = 0; i < 4; i++) o[i] = f32x4{0.f, 0.f, 0.f, 0.f};
  float zp[4] = {0.f, 0.f, 0.f, 0.f};

  int kr = tid >> 3, kc = (tid & 7) * 8;
  int vd = tid >> 2, vk = (tid & 3) * 8;

  const float sc_log2e = 0.18033688f;  // (1/sqrt(64)) * log2(e)

  int nkt = (t0 >> 5) + 2;
  for (int kt = 0; kt < nkt; kt++) {
    int kbase = kt * 32;
    uint4 kv16 = *(const uint4*)(Kb + (size_t)(b * 2048 + kbase + kr) * 512 + kvh * 64 + kc);
    uint4 vv16 = *(const uint4*)(Vt + (size_t)(kvh * 64 + vd) * 4096 + b * 2048 + kbase + vk);
    __syncthreads();
    *(uint4*)(Ks + kr * KLD + kc)  = kv16;
    *(uint4*)(Vst + vd * VLD + vk) = vv16;
    __syncthreads();

    f32x4 sacc[2];
    for (int ks = 0; ks < 2; ks++) {
      sacc[ks] = f32x4{0.f, 0.f, 0.f, 0.f};
      for (int dh = 0; dh < 2; dh++) {
        bf16x8 kf = *(const bf16x8*)(Ks + (ks * 16 + l15) * KLD + dh * 32 + quad * 8);
        sacc[ks] = __builtin_amdgcn_mfma_f32_16x16x32_bf16(qf[dh], kf, sacc[ks], 0, 0, 0);
      }
    }
    for (int ks = 0; ks < 2; ks++) {
      int key = kbase + ks * 16 + l15;
      for (int r = 0; r < 4; r++) {
        int qq = qrow + quad * 4 + r;
        float p = (key <= qq) ? exp2f(sacc[ks][r] * sc_log2e) : 0.f;
        zp[r] += p;
        Ps[wid][(quad * 4 + r) * PLD + ks * 16 + l15] = f2bf(p);
      }
    }
    __syncthreads();

    bf16x8 pf = *(const bf16x8*)(&Ps[wid][l15 * PLD + quad * 8]);
    for (int ns = 0; ns < 4; ns++) {
      bf16x8 vf = *(const bf16x8*)(Vst + (ns * 16 + l15) * VLD + quad * 8);
      o[ns] = __builtin_amdgcn_mfma_f32_16x16x32_bf16(pf, vf, o[ns], 0, 0, 0);
    }
  }

  for (int r = 0; r < 4; r++) {
    float z = zp[r];
    z += __shfl_xor(z, 1);
    z += __shfl_xor(z, 2);
    z += __shfl_xor(z, 4);
    z += __shfl_xor(z, 8);
    zp[r] = z;
  }
  for (int ns = 0; ns < 4; ns++)
    for (int r = 0; r < 4; r++) {
      int row = b * 2048 + qrow + quad * 4 + r;
      Y[(size_t)row * 2048 + h * 64 + ns * 16 + l15] = f2bf(o[ns][r] / zp[r]);
    }
}

extern "C" void kernel_launch(void* const* d_in, const int* in_sizes, int n_in,
                              void* d_out, int out_size, void* d_ws, size_t ws_size,
                              hipStream_t stream) {
  const float* x  = (const float*)d_in[0];  // [4096][2048] fp32
  const float* Wq = (const float*)d_in[1];  // [2048][2048]
  const float* Wk = (const float*)d_in[2];  // [2048][512]
  const float* Wv = (const float*)d_in[3];  // [2048][512]
  const float* Wo = (const float*)d_in[4];  // [2048][2048]
  float* outp = (float*)d_out;              // fp32 OUTPUT (reference dtype)

  // ---- lean workspace layout: 20M u16 = 40 MB total ----
  u16* base = (u16*)d_ws;
  u16* WqT = base;                 // [2048][2048]  4M u16
  u16* WkT = WqT + 4194304;        // [512][2048]   1M
  u16* WvT = WkT + 1048576;        // [512][2048]   1M
  u16* Vb  = WvT + 1048576;        // [4096][512]   2M
  u16* Qb  = Vb  + 2097152;        // [4096][2048]  8M
  u16* Kb  = Qb  + 8388608;        // [4096][512]   2M
  u16* Vt  = Kb  + 2097152;        // [512][4096]   2M
  // reuse (stream-ordered, regions dead by then):
  u16* Yb  = base;                 // [4096][2048]  8M  (over WqT..Vb)
  u16* WoT = Kb;                   // [2048][2048]  4M  (over Kb..Vt, after attn)

  // weight transposes + fp32->bf16 convert
  transpose_cvt<<<dim3(64, 64), 256, 0, stream>>>(Wq, WqT, 2048, 2048);
  transpose_cvt<<<dim3(16, 64), 256, 0, stream>>>(Wk, WkT, 2048, 512);
  transpose_cvt<<<dim3(16, 64), 256, 0, stream>>>(Wv, WvT, 2048, 512);

  // projections (A = fp32 x, converted during LDS staging)
  gemm_a32_bt<<<dim3(32, 64), 256, 0, stream>>>(x, WqT, Qb, 4096, 2048, 2048);
  gemm_a32_bt<<<dim3(8,  64), 256, 0, stream>>>(x, WkT, Kb, 4096, 512, 2048);
  gemm_a32_bt<<<dim3(8,  64), 256, 0, stream>>>(x, WvT, Vb, 4096, 512, 2048);

  // RoPE on Q and K
  rope_kernel<<<(4096 * 1024) / 256, 256, 0, stream>>>(Qb, 2048, 4096 * 1024);
  rope_kernel<<<(4096 * 256)  / 256, 256, 0, stream>>>(Kb, 512,  4096 * 256);

  // V -> V^T for contiguous PV B-frag staging
  transpose_bf16<<<dim3(16, 128), 256, 0, stream>>>(Vb, Vt, 4096, 512);

  // attention (writes Yb over dead WqT/WkT/WvT/Vb)
  attn_kernel<<<dim3(32, 64), 256, 0, stream>>>(Qb, Kb, Vt, Yb);

  // Wo transpose into dead Kb/Vt region, then output projection -> fp32 d_out
  transpose_cvt<<<dim3(64, 64), 256, 0, stream>>>(Wo, WoT, 2048, 2048);
  gemm_bt_f32out<<<dim3(32, 64), 256, 0, stream>>>(Yb, WoT, outp, 4096, 2048, 2048);
}

// Round 8
// 416.181 us; speedup vs baseline: 1.4078x; 1.4078x over previous
//
#include <hip/hip_runtime.h>

using u16 = unsigned short;
using u32 = unsigned int;

typedef __attribute__((ext_vector_type(8))) __bf16 bf16x8;
typedef __attribute__((ext_vector_type(4))) float f32x4;

#define DEVI __device__ __forceinline__

DEVI float bf2f(u16 u) {
  union { u32 i; float f; } v; v.i = ((u32)u) << 16; return v.f;
}
DEVI u16 f2bf(float f) {
  union { float f; u32 u; } v; v.f = f;
  u32 u = v.u;
  u32 r = (u + 0x7fffu + ((u >> 16) & 1u)) >> 16;
  return (u16)r;
}

// async global->LDS, 16B per lane. LDS dest = wave-uniform base + lane*16.
DEVI void gload16(const u16* g, u16* l) {
  __builtin_amdgcn_global_load_lds(
      (const __attribute__((address_space(1))) void*)g,
      (__attribute__((address_space(3))) void*)l, 16, 0, 0);
}

// ---------------- cvt x: fp32 -> bf16, 8 elems/thread ----------------
__global__ __launch_bounds__(256) void cvt_bf16_f32(const float* __restrict__ in,
                                                    u16* __restrict__ out, int n8) {
  int i = blockIdx.x * 256 + threadIdx.x;
  if (i >= n8) return;
  const float4* fin = (const float4*)in;
  float4 a = fin[i * 2], b = fin[i * 2 + 1];
  u16 o[8] = {f2bf(a.x), f2bf(a.y), f2bf(a.z), f2bf(a.w),
              f2bf(b.x), f2bf(b.y), f2bf(b.z), f2bf(b.w)};
  ((uint4*)out)[i] = *(const uint4*)o;
}

// ------- transpose+convert: in[R][Cc] fp32 -> out[Cc][R] bf16 -------
__global__ __launch_bounds__(256) void transpose_cvt(const float* __restrict__ in,
                                                     u16* __restrict__ out,
                                                     int R, int Cc) {
  __shared__ u16 tile[32][33];
  int c0 = blockIdx.x * 32, r0 = blockIdx.y * 32;
  int x  = threadIdx.x & 31;
  int y0 = threadIdx.x >> 5;
  for (int yy = y0; yy < 32; yy += 8)
    tile[yy][x] = f2bf(in[(size_t)(r0 + yy) * Cc + c0 + x]);
  __syncthreads();
  for (int yy = y0; yy < 32; yy += 8)
    out[(size_t)(c0 + yy) * R + r0 + x] = tile[x][yy];
}

// ---- transpose bf16 with input row-stride (for V slice of QKV) ----
__global__ __launch_bounds__(256) void transpose_sl(const u16* __restrict__ in, int ldin,
                                                    u16* __restrict__ out,
                                                    int R, int Cc) {
  __shared__ u16 tile[32][33];
  int c0 = blockIdx.x * 32, r0 = blockIdx.y * 32;
  int x  = threadIdx.x & 31;
  int y0 = threadIdx.x >> 5;
  for (int yy = y0; yy < 32; yy += 8)
    tile[yy][x] = in[(size_t)(r0 + yy) * ldin + c0 + x];
  __syncthreads();
  for (int yy = y0; yy < 32; yy += 8)
    out[(size_t)(c0 + yy) * R + r0 + x] = tile[x][yy];
}

// ---------------- RoPE in place on a Q/K slice (row stride ld) ----------------
__global__ __launch_bounds__(256) void rope_k(u16* __restrict__ X, int ld, int width, int total) {
  int idx = blockIdx.x * 256 + threadIdx.x;
  if (idx >= total) return;
  int ppr  = width >> 1;
  int row  = idx / ppr;
  int rem  = idx - row * ppr;
  int head = rem >> 5;
  int d    = rem & 31;
  int t    = row & 2047;
  float inv = exp2f(-(float)d * 0.59161152f);  // 500000^(-d/32)
  float ang = (float)t * inv;
  float s, c;
  sincosf(ang, &s, &c);
  size_t base = (size_t)row * ld + head * 64 + d;
  float x0 = bf2f(X[base]);
  float x1 = bf2f(X[base + 32]);
  X[base]      = f2bf(x0 * c - x1 * s);
  X[base + 32] = f2bf(x1 * c + x0 * s);
}

// ---- m97-style GEMM: C[M,N] = A[M,K] * Bt[N,K]^T, 128x128 tile, BK=32 ----
// global_load_lds staging + XOR swizzle + EXPLICIT vmcnt(0) before consume-barrier.
DEVI void cstore(u16* C, size_t idx, float v)   { C[idx] = f2bf(v); }
DEVI void cstore(float* C, size_t idx, float v) { C[idx] = v; }

template <typename TO>
__global__ __launch_bounds__(256) void gemm128(const u16* __restrict__ A,
                                               const u16* __restrict__ Bt,
                                               TO* __restrict__ C,
                                               int M, int N, int K) {
  __shared__ u16 As[128 * 32];
  __shared__ u16 Bs[128 * 32];
  int tid = threadIdx.x, wid = tid >> 6, lane = tid & 63;
  int quad = lane >> 4, l15 = lane & 15;
  int m0 = blockIdx.y * 128, n0 = blockIdx.x * 128;
  int wm = (wid >> 1) * 64, wn = (wid & 1) * 64;

  int r0s = wid * 16 + (lane >> 2);
  int r1s = 64 + wid * 16 + (lane >> 2);
  int cblk = lane & 3;
  int cs0 = (cblk ^ ((r0s >> 1) & 3)) * 8;
  int cs1 = (cblk ^ ((r1s >> 1) & 3)) * 8;
  u16* lA0 = As + wid * 512 + lane * 8;
  u16* lA1 = As + (4 + wid) * 512 + lane * 8;
  u16* lB0 = Bs + wid * 512 + lane * 8;
  u16* lB1 = Bs + (4 + wid) * 512 + lane * 8;
  const u16* gA0 = A + (size_t)(m0 + r0s) * K + cs0;
  const u16* gA1 = A + (size_t)(m0 + r1s) * K + cs1;
  const u16* gB0 = Bt + (size_t)(n0 + r0s) * K + cs0;
  const u16* gB1 = Bt + (size_t)(n0 + r1s) * K + cs1;

  f32x4 acc[4][4];
  for (int i = 0; i < 4; i++)
    for (int j = 0; j < 4; j++) acc[i][j] = f32x4{0.f, 0.f, 0.f, 0.f};

  for (int k0 = 0; k0 < K; k0 += 32) {
    __syncthreads();                 // prior iter's frag reads done
    gload16(gA0 + k0, lA0);
    gload16(gA1 + k0, lA1);
    gload16(gB0 + k0, lB0);
    gload16(gB1 + k0, lB1);
    __builtin_amdgcn_s_waitcnt(0x0F70);  // vmcnt(0): force async-LDS drain
    __syncthreads();
    bf16x8 af[4], bf_[4];
    for (int mi = 0; mi < 4; mi++) {
      int row = wm + mi * 16 + l15;
      af[mi] = *(const bf16x8*)(As + row * 32 + ((quad ^ ((row >> 1) & 3)) * 8));
    }
    for (int ni = 0; ni < 4; ni++) {
      int row = wn + ni * 16 + l15;
      bf_[ni] = *(const bf16x8*)(Bs + row * 32 + ((quad ^ ((row >> 1) & 3)) * 8));
    }
    for (int mi = 0; mi < 4; mi++)
      for (int ni = 0; ni < 4; ni++)
        acc[mi][ni] = __builtin_amdgcn_mfma_f32_16x16x32_bf16(af[mi], bf_[ni], acc[mi][ni], 0, 0, 0);
  }
  for (int mi = 0; mi < 4; mi++)
    for (int ni = 0; ni < 4; ni++)
      for (int r = 0; r < 4; r++) {
        int row = m0 + wm + mi * 16 + quad * 4 + r;
        int col = n0 + wn + ni * 16 + l15;
        cstore(C, (size_t)row * N + col, acc[mi][ni][r]);
      }
}

// ---------------- Flash attention: VERBATIM round-5 body ----------------
// (proven-correct). Only change: Q/K read from packed QKV with row stride 3072.
// grid: (32, 64). Q rotated in-memory by rope_k beforehand.
__global__ __launch_bounds__(256) void attn_kernel(const u16* __restrict__ QKV,
                                                   const u16* __restrict__ Vt,
                                                   u16* __restrict__ Y) {
  constexpr int KLD = 72;
  constexpr int VLD = 40;
  constexpr int PLD = 40;
  __shared__ u16 Ks[32 * KLD];     // [key][d]
  __shared__ u16 Vst[64 * VLD];    // [d][key]
  __shared__ u16 Ps[4][16 * PLD];  // per-wave [q][key]

  int tid  = threadIdx.x;
  int wid  = tid >> 6;
  int lane = tid & 63;
  int quad = lane >> 4;
  int l15  = lane & 15;
  int bh = blockIdx.y;
  int b  = bh >> 5;
  int h  = bh & 31;
  int kvh = h >> 2;
  int t0  = blockIdx.x * 64;
  int qrow = t0 + wid * 16;

  bf16x8 qf[2];
  {
    const u16* qp = QKV + (size_t)(b * 2048 + qrow + l15) * 3072 + h * 64 + quad * 8;
    qf[0] = *(const bf16x8*)(qp);
    qf[1] = *(const bf16x8*)(qp + 32);
  }

  f32x4 o[4];
  for (int i = 0; i < 4; i++) o[i] = f32x4{0.f, 0.f, 0.f, 0.f};
  float zp[4] = {0.f, 0.f, 0.f, 0.f};

  int kr = tid >> 3, kc = (tid & 7) * 8;
  int vd = tid >> 2, vk = (tid & 3) * 8;

  const float sc_log2e = 0.18033688f;  // (1/sqrt(64)) * log2(e)

  int nkt = (t0 >> 5) + 2;
  for (int kt = 0; kt < nkt; kt++) {
    int kbase = kt * 32;
    uint4 kv16 = *(const uint4*)(QKV + (size_t)(b * 2048 + kbase + kr) * 3072 + 2048 + kvh * 64 + kc);
    uint4 vv16 = *(const uint4*)(Vt + (size_t)(kvh * 64 + vd) * 4096 + b * 2048 + kbase + vk);
    __syncthreads();
    *(uint4*)(Ks + kr * KLD + kc)  = kv16;
    *(uint4*)(Vst + vd * VLD + vk) = vv16;
    __syncthreads();

    f32x4 sacc[2];
    for (int ks = 0; ks < 2; ks++) {
      sacc[ks] = f32x4{0.f, 0.f, 0.f, 0.f};
      for (int dh = 0; dh < 2; dh++) {
        bf16x8 kf = *(const bf16x8*)(Ks + (ks * 16 + l15) * KLD + dh * 32 + quad * 8);
        sacc[ks] = __builtin_amdgcn_mfma_f32_16x16x32_bf16(qf[dh], kf, sacc[ks], 0, 0, 0);
      }
    }
    for (int ks = 0; ks < 2; ks++) {
      int key = kbase + ks * 16 + l15;
      for (int r = 0; r < 4; r++) {
        int qq = qrow + quad * 4 + r;
        float p = (key <= qq) ? exp2f(sacc[ks][r] * sc_log2e) : 0.f;
        zp[r] += p;
        Ps[wid][(quad * 4 + r) * PLD + ks * 16 + l15] = f2bf(p);
      }
    }
    __syncthreads();

    bf16x8 pf = *(const bf16x8*)(&Ps[wid][l15 * PLD + quad * 8]);
    for (int ns = 0; ns < 4; ns++) {
      bf16x8 vf = *(const bf16x8*)(Vst + (ns * 16 + l15) * VLD + quad * 8);
      o[ns] = __builtin_amdgcn_mfma_f32_16x16x32_bf16(pf, vf, o[ns], 0, 0, 0);
    }
  }

  for (int r = 0; r < 4; r++) {
    float z = zp[r];
    z += __shfl_xor(z, 1);
    z += __shfl_xor(z, 2);
    z += __shfl_xor(z, 4);
    z += __shfl_xor(z, 8);
    zp[r] = z;
  }
  for (int ns = 0; ns < 4; ns++)
    for (int r = 0; r < 4; r++) {
      int row = b * 2048 + qrow + quad * 4 + r;
      Y[(size_t)row * 2048 + h * 64 + ns * 16 + l15] = f2bf(o[ns][r] / zp[r]);
    }
}

extern "C" void kernel_launch(void* const* d_in, const int* in_sizes, int n_in,
                              void* d_out, int out_size, void* d_ws, size_t ws_size,
                              hipStream_t stream) {
  const float* x  = (const float*)d_in[0];  // [4096][2048] fp32
  const float* Wq = (const float*)d_in[1];  // [2048][2048]
  const float* Wk = (const float*)d_in[2];  // [2048][512]
  const float* Wv = (const float*)d_in[3];  // [2048][512]
  const float* Wo = (const float*)d_in[4];  // [2048][2048]
  float* outp = (float*)d_out;              // fp32 out

  // workspace (u16 units), ~59 MB peak
  u16* xb    = (u16*)d_ws;             // [4096][2048]   8388608
  u16* WqkvT = xb + 8388608;           // [3072][2048]   6291456
  u16* QKV   = WqkvT + 6291456;        // [4096][3072]  12582912
  u16* Vt    = QKV + 12582912;         // [512][4096]    2097152
  u16* Yb    = xb;                     // reuse (xb dead after QKV gemm)
  u16* WoT   = WqkvT;                  // reuse (WqkvT dead after QKV gemm)

  // x -> bf16
  cvt_bf16_f32<<<4096, 256, 0, stream>>>(x, xb, 1048576);

  // weights -> transposed bf16, stacked [Wq^T; Wk^T; Wv^T]
  transpose_cvt<<<dim3(64, 64), 256, 0, stream>>>(Wq, WqkvT, 2048, 2048);
  transpose_cvt<<<dim3(16, 64), 256, 0, stream>>>(Wk, WqkvT + (size_t)2048 * 2048, 2048, 512);
  transpose_cvt<<<dim3(16, 64), 256, 0, stream>>>(Wv, WqkvT + (size_t)2560 * 2048, 2048, 512);

  // fused QKV projection: [4096,2048] x [2048,3072] -> [4096,3072]
  gemm128<u16><<<dim3(24, 32), 256, 0, stream>>>(xb, WqkvT, QKV, 4096, 3072, 2048);

  // RoPE on Q and K slices (in place, strided)
  rope_k<<<(4096 * 1024) / 256, 256, 0, stream>>>(QKV, 3072, 2048, 4096 * 1024);
  rope_k<<<(4096 * 256) / 256, 256, 0, stream>>>(QKV + 2048, 3072, 512, 4096 * 256);

  // V slice -> V^T
  transpose_sl<<<dim3(16, 128), 256, 0, stream>>>(QKV + 2560, 3072, Vt, 4096, 512);

  // attention (round-5 proven body) -> Yb
  attn_kernel<<<dim3(32, 64), 256, 0, stream>>>(QKV, Vt, Yb);

  // Wo -> WoT, output projection -> fp32 d_out
  transpose_cvt<<<dim3(64, 64), 256, 0, stream>>>(Wo, WoT, 2048, 2048);
  gemm128<float><<<dim3(16, 32), 256, 0, stream>>>(Yb, WoT, outp, 4096, 2048, 2048);
}